// Round 10
// baseline (431.248 us; speedup 1.0000x reference)
//
#include <hip/hip_runtime.h>

// Problem constants (B=8, Q=512, D=4096, H=1024)
#define BATCH 8
#define QLEN 512
#define DLEN 4096
#define HDIM 1024

// ---------- helpers ----------
typedef __attribute__((ext_vector_type(8))) short bf16x8;   // 8 bf16 in 4 VGPRs
typedef __attribute__((ext_vector_type(4))) float f32x4;
typedef __attribute__((ext_vector_type(4))) short s16x4;

__device__ __forceinline__ short f2bf(float f) {
    union { float f; unsigned u; } x; x.f = f;
    unsigned r = x.u + 0x7fffu + ((x.u >> 16) & 1u);   // RNE
    return (short)(r >> 16);
}

__device__ __forceinline__ void gload_lds16(const void* g, void* l) {
    __builtin_amdgcn_global_load_lds(
        (const __attribute__((address_space(1))) unsigned int*)g,
        (__attribute__((address_space(3))) unsigned int*)l,
        16, 0, 0);
}

#define WAIT_VMCNT(n) asm volatile("s_waitcnt vmcnt(" #n ")" ::: "memory")

// ---------- prep kernels ----------
__global__ void cvt_f32_bf16(const float* __restrict__ in, short* __restrict__ out, int n4) {
    int i = blockIdx.x * blockDim.x + threadIdx.x;
    int stride = gridDim.x * blockDim.x;
    for (; i < n4; i += stride) {
        float4 x = ((const float4*)in)[i];
        s16x4 o = { f2bf(x.x), f2bf(x.y), f2bf(x.z), f2bf(x.w) };
        ((s16x4*)out)[i] = o;
    }
}

// proj_w [h][k] f32 -> Wt [k][h] bf16  (1024x1024), 32x32 LDS tile transpose
__global__ void transpose_w(const float* __restrict__ W, short* __restrict__ Wt) {
    __shared__ float t[32][33];
    const int hb = blockIdx.y * 32, kb = blockIdx.x * 32;
    #pragma unroll
    for (int i = 0; i < 4; ++i) {
        int h = threadIdx.y + i * 8;
        t[h][threadIdx.x] = W[(size_t)(hb + h) * HDIM + kb + threadIdx.x];
    }
    __syncthreads();
    #pragma unroll
    for (int i = 0; i < 4; ++i) {
        int k = threadIdx.y + i * 8;
        Wt[(size_t)(kb + k) * HDIM + hb + threadIdx.x] = f2bf(t[threadIdx.x][k]);
    }
}

// docsB [b][d][h] bf16 -> docsT [b][h][d] bf16. 64x64 tile via uint LDS [64][65]
__global__ void transpose_docs(const short* __restrict__ docsB, short* __restrict__ docsT) {
    __shared__ unsigned t[64][65];
    const int b = blockIdx.z;
    const int h0 = blockIdx.x * 64, d0 = blockIdx.y * 64;
    const int tq = threadIdx.x & 15;
    const int tr = threadIdx.x >> 4;
    #pragma unroll
    for (int i = 0; i < 4; ++i) {
        int d = tr + i * 16;
        s16x4 v = *(const s16x4*)(docsB + ((size_t)b * DLEN + d0 + d) * HDIM + h0 + tq * 4);
        t[d][tq * 4 + 0] = (unsigned short)v[0];
        t[d][tq * 4 + 1] = (unsigned short)v[1];
        t[d][tq * 4 + 2] = (unsigned short)v[2];
        t[d][tq * 4 + 3] = (unsigned short)v[3];
    }
    __syncthreads();
    #pragma unroll
    for (int i = 0; i < 4; ++i) {
        int h = tr + i * 16;
        s16x4 o = { (short)t[tq * 4 + 0][h], (short)t[tq * 4 + 1][h],
                    (short)t[tq * 4 + 2][h], (short)t[tq * 4 + 3][h] };
        *(s16x4*)(docsT + ((size_t)b * HDIM + h0 + h) * DLEN + d0 + tq * 4) = o;
    }
}

// ---------- GEMM-128 (GEMM1): 128x128, BK=32, 4 slots, prefetch distance 3 ----------
// Counted-vmcnt loop (R6-proven sync invariants, depth 2->3 for 900cy HBM latency):
//   iter t: stage tile t+3 -> slot (t+3)%4; ds_read frags + 16 MFMA from slot t%4;
//   wait ladder: t+3<nt -> vmcnt(8); t+2<nt -> vmcnt(4); else vmcnt(0); s_barrier.
//   WAR: slot(t+3)%4 == slot(t-1)%4, reads done before iter t-1's barrier ✓
//   RAW: tile t+1 retired by per-wave vmcnt (FIFO: outstanding = t+2,t+3) + barrier ✓
// XOR chunk-swizzle: phys = cc ^ ((row>>1)&3); linear LDS dest, pre-swizzled source.
#define G1BM 128
#define G1BK 32
#define G1TS (G1BM * G1BK)   // 4096 shorts = 8 KB

__global__ void gemm128_bias(const short* __restrict__ A, const short* __restrict__ B,
                             short* __restrict__ C, const float* __restrict__ bias,
                             int N, int Kstride, int Kloop, int sx, int sxy) {
    __shared__ short As[4 * G1TS];   // 32 KB
    __shared__ short Bs[4 * G1TS];   // 32 KB
    const int tid  = threadIdx.x;
    const int lane = tid & 63;
    const int wv   = tid >> 6;
    const int wr   = wv >> 1, wc = wv & 1;

    const int wg = (blockIdx.x & 7) * (gridDim.x >> 3) + (blockIdx.x >> 3);
    const int bx = wg & ((1 << sx) - 1);
    const int by = (wg >> sx) & ((1 << (sxy - sx)) - 1);

    const size_t rowBase = (size_t)by * G1BM;
    const size_t colBase = (size_t)bx * G1BM;

    f32x4 acc[4][4];
    #pragma unroll
    for (int m = 0; m < 4; ++m)
        #pragma unroll
        for (int n = 0; n < 4; ++n)
            acc[m][n] = (f32x4){0.f, 0.f, 0.f, 0.f};

    const short* aSrc[2]; const short* bSrc[2]; int dOff[2];
    #pragma unroll
    for (int i = 0; i < 2; ++i) {
        const int c = tid + 256 * i;            // 0..511
        const int r = c >> 2, cc = c & 3;
        const int gk = (cc ^ ((r >> 1) & 3)) << 3;
        aSrc[i] = A + (rowBase + r) * (size_t)Kstride + gk;
        bSrc[i] = B + (colBase + r) * (size_t)Kstride + gk;
        dOff[i] = c * 8;
    }
    const int chunkL = lane >> 4;
    const int lr = lane & 15;

    const int nt = Kloop / G1BK;                // 32

    // prologue: tiles 0,1,2 -> slots 0,1,2; wait tile 0 (tiles 1,2 keep flying)
    #pragma unroll
    for (int s = 0; s < 3; ++s) {
        #pragma unroll
        for (int i = 0; i < 2; ++i) gload_lds16(aSrc[i] + s * G1BK, As + s * G1TS + dOff[i]);
        #pragma unroll
        for (int i = 0; i < 2; ++i) gload_lds16(bSrc[i] + s * G1BK, Bs + s * G1TS + dOff[i]);
    }
    WAIT_VMCNT(8);
    __builtin_amdgcn_s_barrier();

    for (int t = 0; t < nt; ++t) {
        if (t + 3 < nt) {
            const int kt = (t + 3) * G1BK;
            const int o = ((t + 3) & 3) * G1TS;
            #pragma unroll
            for (int i = 0; i < 2; ++i) gload_lds16(aSrc[i] + kt, As + o + dOff[i]);
            #pragma unroll
            for (int i = 0; i < 2; ++i) gload_lds16(bSrc[i] + kt, Bs + o + dOff[i]);
        }

        const short* Ab = As + (t & 3) * G1TS;
        const short* Bb = Bs + (t & 3) * G1TS;
        bf16x8 af[4], bfr[4];
        #pragma unroll
        for (int m = 0; m < 4; ++m) {
            const int row = wr * 64 + m * 16 + lr;
            af[m] = *(const bf16x8*)(Ab + row * G1BK + ((chunkL ^ ((row >> 1) & 3)) << 3));
        }
        #pragma unroll
        for (int n = 0; n < 4; ++n) {
            const int row = wc * 64 + n * 16 + lr;
            bfr[n] = *(const bf16x8*)(Bb + row * G1BK + ((chunkL ^ ((row >> 1) & 3)) << 3));
        }
        #pragma unroll
        for (int m = 0; m < 4; ++m)
            #pragma unroll
            for (int n = 0; n < 4; ++n)
                acc[m][n] = __builtin_amdgcn_mfma_f32_16x16x32_bf16(af[m], bfr[n], acc[m][n], 0, 0, 0);

        if (t + 1 < nt) {
            if (t + 3 < nt)      { WAIT_VMCNT(8); }  // tiles t+2,t+3 in flight
            else if (t + 2 < nt) { WAIT_VMCNT(4); }  // tile t+2 in flight
            else                 { WAIT_VMCNT(0); }
            __builtin_amdgcn_sched_barrier(0);
            __builtin_amdgcn_s_barrier();
            __builtin_amdgcn_sched_barrier(0);
        }
    }

    const int orow = (lane >> 4) << 2;
    const int ocol = lane & 15;
    #pragma unroll
    for (int n = 0; n < 4; ++n) {
        const size_t col = colBase + wc * 64 + n * 16 + ocol;
        const float bv = bias[col];
        #pragma unroll
        for (int m = 0; m < 4; ++m) {
            const size_t rbase = rowBase + wr * 64 + m * 16 + orow;
            #pragma unroll
            for (int j = 0; j < 4; ++j)
                C[(rbase + j) * (size_t)N + col] = f2bf(acc[m][n][j] + bv);
        }
    }
}

// ---------- GEMM-256: 256x256, 8 waves (2Mx4N), BK=32, 4 slots, distance 3 ----------
// Same counted-vmcnt invariants as gemm128_bias; 32 MFMA : 12 ds_read per wave-iter.
// EPI 1: f32 out * scale   EPI 2: f32 out (split-K partials)
#define G2BM 256
#define G2BK 32
#define G2TS (G2BM * G2BK)   // 8192 shorts = 16 KB per operand per slot

template<int EPI>
__launch_bounds__(512, 1)
__global__ void gemm256(const short* __restrict__ A, const short* __restrict__ B,
                        float* __restrict__ Cv, float scale,
                        int N, int Kstride, int Kloop, int kOffStep,
                        int sx, int sxy,
                        long long aB, long long bB, long long cB) {
    __shared__ short As[4 * G2TS];   // 64 KB
    __shared__ short Bs[4 * G2TS];   // 64 KB
    const int tid  = threadIdx.x;
    const int lane = tid & 63;
    const int wv   = tid >> 6;        // 0..7
    const int wm   = wv >> 2;         // 0..1 : M-half
    const int wn   = wv & 3;          // 0..3 : N-quarter

    const int wg = (blockIdx.x & 7) * (gridDim.x >> 3) + (blockIdx.x >> 3);
    const int bx = wg & ((1 << sx) - 1);
    const int by = (wg >> sx) & ((1 << (sxy - sx)) - 1);
    const int z  = wg >> sxy;

    const size_t rowBase = (size_t)by * G2BM;
    const size_t colBase = (size_t)bx * G2BM;
    const int bb = z & 7;
    const int kOff = (z >> 3) * kOffStep;
    const short* Ag = A + (size_t)bb * aB + kOff;
    const short* Bg = B + (size_t)bb * bB + kOff;

    f32x4 acc[8][4];
    #pragma unroll
    for (int m = 0; m < 8; ++m)
        #pragma unroll
        for (int n = 0; n < 4; ++n)
            acc[m][n] = (f32x4){0.f, 0.f, 0.f, 0.f};

    const short* aSrc[2]; const short* bSrc[2]; int dOff[2];
    #pragma unroll
    for (int i = 0; i < 2; ++i) {
        const int c = tid + 512 * i;             // 0..1023
        const int r = c >> 2, cc = c & 3;
        const int gk = (cc ^ ((r >> 1) & 3)) << 3;
        aSrc[i] = Ag + (rowBase + r) * (size_t)Kstride + gk;
        bSrc[i] = Bg + (colBase + r) * (size_t)Kstride + gk;
        dOff[i] = c * 8;
    }
    const int chunkL = lane >> 4;
    const int lr = lane & 15;

    const int nt = Kloop / G2BK;                 // 32

    // prologue: tiles 0,1,2 -> slots 0,1,2; wait tile 0
    #pragma unroll
    for (int s = 0; s < 3; ++s) {
        #pragma unroll
        for (int i = 0; i < 2; ++i) gload_lds16(aSrc[i] + s * G2BK, As + s * G2TS + dOff[i]);
        #pragma unroll
        for (int i = 0; i < 2; ++i) gload_lds16(bSrc[i] + s * G2BK, Bs + s * G2TS + dOff[i]);
    }
    WAIT_VMCNT(8);
    __builtin_amdgcn_s_barrier();

    for (int t = 0; t < nt; ++t) {
        if (t + 3 < nt) {
            const int kt = (t + 3) * G2BK;
            const int o = ((t + 3) & 3) * G2TS;
            #pragma unroll
            for (int i = 0; i < 2; ++i) gload_lds16(aSrc[i] + kt, As + o + dOff[i]);
            #pragma unroll
            for (int i = 0; i < 2; ++i) gload_lds16(bSrc[i] + kt, Bs + o + dOff[i]);
        }

        const short* Ab = As + (t & 3) * G2TS;
        const short* Bb = Bs + (t & 3) * G2TS;
        bf16x8 bfr[4], af[8];
        #pragma unroll
        for (int n = 0; n < 4; ++n) {
            const int row = wn * 64 + n * 16 + lr;
            bfr[n] = *(const bf16x8*)(Bb + row * G2BK + ((chunkL ^ ((row >> 1) & 3)) << 3));
        }
        #pragma unroll
        for (int m = 0; m < 8; ++m) {
            const int row = wm * 128 + m * 16 + lr;
            af[m] = *(const bf16x8*)(Ab + row * G2BK + ((chunkL ^ ((row >> 1) & 3)) << 3));
        }
        #pragma unroll
        for (int m = 0; m < 8; ++m)
            #pragma unroll
            for (int n = 0; n < 4; ++n)
                acc[m][n] = __builtin_amdgcn_mfma_f32_16x16x32_bf16(af[m], bfr[n], acc[m][n], 0, 0, 0);

        if (t + 1 < nt) {
            if (t + 3 < nt)      { WAIT_VMCNT(8); }
            else if (t + 2 < nt) { WAIT_VMCNT(4); }
            else                 { WAIT_VMCNT(0); }
            __builtin_amdgcn_sched_barrier(0);
            __builtin_amdgcn_s_barrier();
            __builtin_amdgcn_sched_barrier(0);
        }
    }

    const int orow = (lane >> 4) << 2;
    const int ocol = lane & 15;
    #pragma unroll
    for (int n = 0; n < 4; ++n) {
        const size_t col = colBase + wn * 64 + n * 16 + ocol;
        #pragma unroll
        for (int m = 0; m < 8; ++m) {
            const size_t rbase = rowBase + wm * 128 + m * 16 + orow;
            #pragma unroll
            for (int j = 0; j < 4; ++j) {
                const float v = acc[m][n][j];
                const size_t off = (size_t)z * cB + (rbase + j) * (size_t)N + col;
                Cv[off] = (EPI == 1) ? v * scale : v;
            }
        }
    }
}

// ---------- split-K reduce: out4[i] = sum_{s<4} p4[i + s*2^20] ----------
__global__ void reduce4(const float* __restrict__ p, float* __restrict__ out, int n4) {
    int i = blockIdx.x * blockDim.x + threadIdx.x;
    const int stride = gridDim.x * blockDim.x;
    const float4* p4 = (const float4*)p;
    float4* o4 = (float4*)out;
    for (; i < n4; i += stride) {
        float4 a = p4[i];
        float4 b = p4[i + 1048576];
        float4 c = p4[i + 2097152];
        float4 d = p4[i + 3145728];
        float4 r;
        r.x = a.x + b.x + c.x + d.x;
        r.y = a.y + b.y + c.y + d.y;
        r.z = a.z + b.z + c.z + d.z;
        r.w = a.w + b.w + c.w + d.w;
        o4[i] = r;
    }
}

// ---------- masked row softmax over D=4096; writes f32 output + bf16 copy ----------
__global__ void softmax_rows(const float* __restrict__ scores, const int* __restrict__ mask,
                             float* __restrict__ attnF, short* __restrict__ attnB) {
    const int row = blockIdx.x;          // b*Q + q
    const int b   = row >> 9;            // / QLEN
    const int tid = threadIdx.x;
    const int lane = tid & 63;
    const int wv = tid >> 6;
    const float4* S  = (const float4*)(scores + (size_t)row * DLEN);
    const int4*   Mk = (const int4*)(mask + (size_t)b * DLEN);
    __shared__ float red[8];

    float v[16];
    float mx = -INFINITY;
    #pragma unroll
    for (int i = 0; i < 4; ++i) {
        float4 s = S[i * 256 + tid];
        int4   m = Mk[i * 256 + tid];
        v[i * 4 + 0] = m.x ? s.x : -INFINITY;
        v[i * 4 + 1] = m.y ? s.y : -INFINITY;
        v[i * 4 + 2] = m.z ? s.z : -INFINITY;
        v[i * 4 + 3] = m.w ? s.w : -INFINITY;
        #pragma unroll
        for (int c = 0; c < 4; ++c) mx = fmaxf(mx, v[i * 4 + c]);
    }
    #pragma unroll
    for (int o = 32; o > 0; o >>= 1) mx = fmaxf(mx, __shfl_xor(mx, o));
    if (lane == 0) red[wv] = mx;
    __syncthreads();
    mx = fmaxf(fmaxf(red[0], red[1]), fmaxf(red[2], red[3]));

    float sum = 0.f;
    #pragma unroll
    for (int i = 0; i < 16; ++i) {
        float e = __expf(v[i] - mx);   // masked: exp(-inf) = 0
        v[i] = e;
        sum += e;
    }
    #pragma unroll
    for (int o = 32; o > 0; o >>= 1) sum += __shfl_xor(sum, o);
    __syncthreads();
    if (lane == 0) red[4 + wv] = sum;
    __syncthreads();
    sum = red[4] + red[5] + red[6] + red[7];
    const float inv = 1.0f / sum;

    float4* OF = (float4*)(attnF + (size_t)row * DLEN);
    s16x4*  OB = (s16x4*)(attnB + (size_t)row * DLEN);
    #pragma unroll
    for (int i = 0; i < 4; ++i) {
        float4 w;
        w.x = v[i * 4 + 0] * inv;
        w.y = v[i * 4 + 1] * inv;
        w.z = v[i * 4 + 2] * inv;
        w.w = v[i * 4 + 3] * inv;
        OF[i * 256 + tid] = w;
        s16x4 o = { f2bf(w.x), f2bf(w.y), f2bf(w.z), f2bf(w.w) };
        OB[i * 256 + tid] = o;
    }
}

// ---------- launch ----------
extern "C" void kernel_launch(void* const* d_in, const int* in_sizes, int n_in,
                              void* d_out, int out_size, void* d_ws, size_t ws_size,
                              hipStream_t stream) {
    const float* qe   = (const float*)d_in[0];   // [8,512,1024]
    const float* docs = (const float*)d_in[1];   // [8,4096,1024]
    const int*   mask = (const int*)d_in[2];     // [8,4096]
    const float* pw   = (const float*)d_in[3];   // [1024,1024]
    const float* pb   = (const float*)d_in[4];   // [1024]

    float* outRet  = (float*)d_out;                          // [8,512,1024]
    float* outAttn = outRet + (size_t)BATCH * QLEN * HDIM;   // [8,512,4096]

    // workspace layout (bytes)
    char* ws = (char*)d_ws;
    short* qeB   = (short*)(ws + 0);            //  8 MiB: [4096][1024] bf16
    short* wt    = (short*)(ws + 8388608);      //  2 MiB: Wt [k][h] bf16
    short* qpB   = (short*)(ws + 10485760);     //  8 MiB: projected q bf16
    short* docsB = (short*)(ws + 18874368);     // 64 MiB: docs bf16 [b][d][h]
    short* docsT = (short*)(ws + 85983232);     // 64 MiB: docsT bf16 [b][h][d]
    float* scor  = (float*)(ws + 153092096);    // 64 MiB: scores f32 / GEMM3 partials
    short* attnB = (short*)(ws + 220200960);    // 32 MiB: attn bf16 [b][q][d]

    // prep: streaming cvt passes + bf16 transpose (reads L2/L3-hot docsB)
    cvt_f32_bf16<<<dim3(1024), dim3(256), 0, stream>>>(qe, qeB, (BATCH * QLEN * HDIM) / 4);
    cvt_f32_bf16<<<dim3(2048), dim3(256), 0, stream>>>(docs, docsB, (BATCH * DLEN * HDIM) / 4);
    transpose_w<<<dim3(32, 32), dim3(32, 8), 0, stream>>>(pw, wt);
    transpose_docs<<<dim3(HDIM / 64, DLEN / 64, BATCH), dim3(256), 0, stream>>>(docsB, docsT);

    // GEMM1: q = qe @ W + b   (M=4096, N=1024, K=1024) -> bf16
    // grid 256 = 8(x) * 32(y): sx=3, sxy=8
    gemm128_bias<<<dim3(256), dim3(256), 0, stream>>>(
        qeB, wt, qpB, pb, HDIM, HDIM, HDIM, 3, 8);

    // GEMM2: scores = q @ docs^T * scale  (per batch M=512, N=4096, K=1024) -> f32
    // grid 256 = 16(x) * 2(y) * 8(z): sx=4, sxy=5
    gemm256<1><<<dim3(256), dim3(512), 0, stream>>>(
        qpB, docsB, scor, 0.03125f, DLEN, HDIM, HDIM, 0, 4, 5,
        (long long)QLEN * HDIM, (long long)DLEN * HDIM, (long long)QLEN * DLEN);

    // softmax rows (4096 rows of 4096) -> f32 output + bf16 for PV
    softmax_rows<<<dim3(BATCH * QLEN), dim3(256), 0, stream>>>(scor, mask, outAttn, attnB);

    // GEMM3 split-K=4: partial[z=split*8+b] = attn @ docs over K-chunk of 1024
    // grid 256 = 4(x) * 2(y) * 32(z): sx=2, sxy=3; partials overwrite scor
    gemm256<2><<<dim3(256), dim3(512), 0, stream>>>(
        attnB, docsT, scor, 1.f, HDIM, DLEN, DLEN / 4, DLEN / 4, 2, 3,
        (long long)QLEN * DLEN, (long long)HDIM * DLEN, (long long)QLEN * HDIM);

    // reduce partials -> retrieved docs
    reduce4<<<dim3(2048), dim3(256), 0, stream>>>(scor, outRet, (BATCH * QLEN * HDIM) / 4);
}